// Round 4
// baseline (60940.704 us; speedup 1.0000x reference)
//
#include <hip/hip_runtime.h>
#include <hip/hip_bf16.h>

typedef __attribute__((ext_vector_type(8))) short  short8;   // 8 x bf16 (MFMA frag)
typedef __attribute__((ext_vector_type(4))) float  f32x4;
typedef __attribute__((ext_vector_type(2))) unsigned int uint2v;

#define NSTEPS 100
#define HSTEP  0.2f

// ---- RK45 (Dormand-Prince) coefficients ----
#define A21 (0.2f)
#define A31 (3.0f/40.0f)
#define A32 (9.0f/40.0f)
#define A41 (44.0f/45.0f)
#define A42 (-56.0f/15.0f)
#define A43 (32.0f/9.0f)
#define A51 (19372.0f/6561.0f)
#define A52 (-25360.0f/2187.0f)
#define A53 (64448.0f/6561.0f)
#define A54 (-212.0f/729.0f)
#define A61 (9017.0f/3168.0f)
#define A62 (-355.0f/33.0f)
#define A63 (46732.0f/5247.0f)
#define A64 (49.0f/176.0f)
#define A65 (-5103.0f/18656.0f)
#define B1  (35.0f/384.0f)
#define B3  (500.0f/1113.0f)
#define B4  (125.0f/192.0f)
#define B5  (-2187.0f/6784.0f)
#define B6  (11.0f/84.0f)

// d_ws layout (bytes):
//   [0,        512K)  Aw   : bf16 A in MFMA-frag order
//   [512K,     520K)  ctr  : 64 counters, 128B apart (memset 0 each launch)
//   [1M,       3M  )  Ybuf : 2 parity x 64 group x 4 quarter x 4KB bf16 Y-slices
#define WS_CTR  (512u * 1024u)
#define WS_YB   (1024u * 1024u)

__device__ __forceinline__ unsigned short f2bf(float f) {
    union { float f; unsigned u; } v; v.f = f;
    unsigned r = v.u + 0x7FFFu + ((v.u >> 16) & 1u);   // RNE
    return (unsigned short)(r >> 16);
}

// Pack A (f32 row-major [row][k]) into bf16 MFMA A-fragment stream order:
// slot fk = T*16+kk, lane: holds A[T*16 + (lane&15)][kk*32 + (lane>>4)*8 + 0..7]
__global__ void pack_A_kernel(const float* __restrict__ A, short* __restrict__ Aw) {
    int t    = blockIdx.x * blockDim.x + threadIdx.x;   // 0..32767
    int lane = t & 63;
    int fk   = t >> 6;
    int kk   = fk & 15;
    int T    = fk >> 4;
    int row  = T * 16 + (lane & 15);
    int kb   = kk * 32 + (lane >> 4) * 8;
    const float* src = A + row * 512 + kb;
    short8 v;
#pragma unroll
    for (int e = 0; e < 8; ++e) v[e] = (short)f2bf(src[e]);
    *(short8*)(Aw + (size_t)t * 8) = v;
}

__global__ __launch_bounds__(512, 1) void mbpert_kernel(
    const float* __restrict__ x, const float* __restrict__ p,
    const float* __restrict__ r, const float* __restrict__ eps,
    const short* __restrict__ Aw, unsigned* __restrict__ ctr,
    short* __restrict__ Ybuf, float* __restrict__ out)
{
    __shared__ __align__(16) char Alds[128 * 1024]; // this WG's 128 A rows, frag order
    __shared__ __align__(16) char Ylds[16 * 1024];  // full 512-row x 16-col Y, bf16, swizzled

    const int bid  = blockIdx.x;
    const int g    = bid >> 2;        // column group: cols [g*16, g*16+16)
    const int q    = bid & 3;         // row quarter: rows [q*128, q*128+128)
    const int tid  = threadIdx.x;
    const int wave = tid >> 6;        // 0..7: rows q*128 + wave*16 .. +16
    const int lane = tid & 63;
    const int cl   = lane & 15;       // MFMA col
    const int gq   = lane >> 4;
    const int col  = g * 16 + cl;
    const int swz  = (cl & 7) << 4;   // Ylds XOR swizzle (bits 4-6)
    const int rloc = wave * 16 + gq * 4;   // local row base (0..127), mult of 4
    const int rg   = q * 128 + rloc;       // global row base

    unsigned* cptr = ctr + g * 32;    // group counter, 128B padded

    // ---- one-time: stage this WG's 128x512 A slice (128 KB, frag order) into LDS ----
    {
        const short* Asl = Aw + q * 65536;   // contiguous frag block for rows [q*128, ..)
#pragma unroll
        for (int i = 0; i < 16; ++i) {
            size_t slot = (size_t)i * 512 + tid;        // 16B slots
            *(short8*)(Alds + slot * 16) = *(const short8*)(Asl + slot * 8);
        }
    }

    // ---- per-thread state: 4 rows x 1 col ----
    f32x4 X0, W, K1, K2, K3, K4, K5;
    X0 = *(const f32x4*)(x + col * 512 + rg);           // Fortran x[col*512+row]
#pragma unroll
    for (int j = 0; j < 4; ++j) {
        const int row = rg + j;
        W[j] = r[row] + eps[row] * p[row * 1024 + col]; // stage-invariant r + eps*p
    }
    __syncthreads();   // Alds ready

    int ex = 0;        // exchange index 0..599

    // One RK stage: publish Y (regs) -> sync 4 peers -> full Y in Ylds -> A@Y -> k
    auto STAGE = [&](f32x4 Yv) -> f32x4 {
        // pack own 4 values to bf16
        uint2v u;
        u.x = (unsigned)f2bf(Yv[0]) | ((unsigned)f2bf(Yv[1]) << 16);
        u.y = (unsigned)f2bf(Yv[2]) | ((unsigned)f2bf(Yv[3]) << 16);
        // own rows -> Ylds (previous matmul's trailing barrier makes this safe)
        *(uint2v*)(Ylds + cl * 1024 + ((rg * 2) ^ swz)) = u;
        // own rows -> global slot [par][g][q], layout [col][row_local] bf16
        short* slot = Ybuf + ((size_t)((ex & 1) * 64 + g) * 4 + q) * 2048;
        *(uint2v*)(slot + cl * 128 + rloc) = u;

        __threadfence();          // release: Y-slice visible at device scope
        __syncthreads();          // whole WG published
        if (tid == 0) atomicAdd(cptr, 1u);
        const unsigned tgt = 4u * (unsigned)(ex + 1);
        while (__hip_atomic_load(cptr, __ATOMIC_RELAXED, __HIP_MEMORY_SCOPE_AGENT) < tgt)
            __builtin_amdgcn_s_sleep(1);
        __threadfence();          // acquire: invalidate stale peer lines

        // pull 3 peers' 4KB slices -> Ylds (coalesced: 32 consecutive tids = 256B run)
        const int   pcol = tid >> 5;        // 0..15
        const int   prq  = tid & 31;        // row quad 0..31
        const short* pb  = Ybuf + (size_t)((ex & 1) * 64 + g) * 4 * 2048;
#pragma unroll
        for (int j = 1; j <= 3; ++j) {
            const int qq = (q + j) & 3;
            uint2v v = *(const uint2v*)(pb + qq * 2048 + pcol * 128 + prq * 4);
            const int prg = qq * 128 + prq * 4;
            *(uint2v*)(Ylds + pcol * 1024 + ((prg * 2) ^ ((pcol & 7) << 4))) = v;
        }
        __syncthreads();          // full Y ready

        // Z = A_slice @ Y for this wave's 16x16 tile
        f32x4 acc = (f32x4){0.f, 0.f, 0.f, 0.f};
#pragma unroll
        for (int kk = 0; kk < 16; ++kk) {
            short8 a = *(const short8*)(Alds + (wave * 16 + kk) * 1024 + lane * 16);
            short8 b = *(const short8*)(Ylds + cl * 1024 + ((kk * 64 + gq * 16) ^ swz));
            acc = __builtin_amdgcn_mfma_f32_16x16x32_bf16(a, b, acc, 0, 0, 0);
        }
        __syncthreads();          // Ylds consumption complete (next stage overwrites)
        ++ex;
        return Yv * (W + acc);
    };

#pragma unroll 1
    for (int s = 0; s < NSTEPS; ++s) {
        K1 = STAGE(X0);
        K2 = STAGE(X0 + HSTEP * (A21 * K1));
        K3 = STAGE(X0 + HSTEP * (A31 * K1 + A32 * K2));
        K4 = STAGE(X0 + HSTEP * (A41 * K1 + A42 * K2 + A43 * K3));
        K5 = STAGE(X0 + HSTEP * (A51 * K1 + A52 * K2 + A53 * K3 + A54 * K4));
        f32x4 K6 = STAGE(X0 + HSTEP * (A61 * K1 + A62 * K2 + A63 * K3 + A64 * K4 + A65 * K5));
        X0 = X0 + HSTEP * (B1 * K1 + B3 * K3 + B4 * K4 + B5 * K5 + B6 * K6);
    }

    // Fortran flatten: out[col*512 + row]
    *(f32x4*)(out + col * 512 + rg) = X0;
}

extern "C" void kernel_launch(void* const* d_in, const int* in_sizes, int n_in,
                              void* d_out, int out_size, void* d_ws, size_t ws_size,
                              hipStream_t stream)
{
    const float* x   = (const float*)d_in[0];
    const float* p   = (const float*)d_in[1];
    const float* r   = (const float*)d_in[2];
    const float* A   = (const float*)d_in[3];
    const float* eps = (const float*)d_in[4];
    float* out = (float*)d_out;

    short*    Aw   = (short*)d_ws;
    unsigned* ctr  = (unsigned*)((char*)d_ws + WS_CTR);
    short*    Ybuf = (short*)((char*)d_ws + WS_YB);

    hipMemsetAsync(ctr, 0, 64 * 128, stream);               // zero group counters
    hipLaunchKernelGGL(pack_A_kernel, dim3(128), dim3(256), 0, stream, A, Aw);
    hipLaunchKernelGGL(mbpert_kernel, dim3(256), dim3(512), 0, stream,
                       x, p, r, eps, Aw, ctr, Ybuf, out);
}

// Round 6
// 1802.195 us; speedup vs baseline: 33.8147x; 33.8147x over previous
//
#include <hip/hip_runtime.h>
#include <hip/hip_bf16.h>

typedef __attribute__((ext_vector_type(8))) short  short8;   // 8 x bf16 (MFMA frag)
typedef __attribute__((ext_vector_type(4))) float  f32x4;
typedef __attribute__((ext_vector_type(2))) unsigned int uint2v;

#define NSTEPS 100
#define HSTEP  0.2f

// ---- RK45 (Dormand-Prince) coefficients ----
#define A21 (0.2f)
#define A31 (3.0f/40.0f)
#define A32 (9.0f/40.0f)
#define A41 (44.0f/45.0f)
#define A42 (-56.0f/15.0f)
#define A43 (32.0f/9.0f)
#define A51 (19372.0f/6561.0f)
#define A52 (-25360.0f/2187.0f)
#define A53 (64448.0f/6561.0f)
#define A54 (-212.0f/729.0f)
#define A61 (9017.0f/3168.0f)
#define A62 (-355.0f/33.0f)
#define A63 (46732.0f/5247.0f)
#define A64 (49.0f/176.0f)
#define A65 (-5103.0f/18656.0f)
#define B1  (35.0f/384.0f)
#define B3  (500.0f/1113.0f)
#define B4  (125.0f/192.0f)
#define B5  (-2187.0f/6784.0f)
#define B6  (11.0f/84.0f)

// d_ws layout (bytes):
//   [0,        512K)  Aw   : bf16 A in MFMA-frag order
//   [512K,     520K)  ctr  : 64 counters, 128B apart (memset 0 each launch)
//   [1M,       3M  )  Ybuf : 2 parity x 64 group x 4 quarter x 4KB bf16 Y-slices
#define WS_CTR  (512u * 1024u)
#define WS_YB   (1024u * 1024u)

__device__ __forceinline__ unsigned short f2bf(float f) {
    union { float f; unsigned u; } v; v.f = f;
    unsigned r = v.u + 0x7FFFu + ((v.u >> 16) & 1u);   // RNE
    return (unsigned short)(r >> 16);
}

// Pack A (f32 row-major [row][k]) into bf16 MFMA A-fragment stream order:
// slot fk = T*16+kk, lane: holds A[T*16 + (lane&15)][kk*32 + (lane>>4)*8 + 0..7]
__global__ void pack_A_kernel(const float* __restrict__ A, short* __restrict__ Aw) {
    int t    = blockIdx.x * blockDim.x + threadIdx.x;   // 0..32767
    int lane = t & 63;
    int fk   = t >> 6;
    int kk   = fk & 15;
    int T    = fk >> 4;
    int row  = T * 16 + (lane & 15);
    int kb   = kk * 32 + (lane >> 4) * 8;
    const float* src = A + row * 512 + kb;
    short8 v;
#pragma unroll
    for (int e = 0; e < 8; ++e) v[e] = (short)f2bf(src[e]);
    *(short8*)(Aw + (size_t)t * 8) = v;
}

__global__ __launch_bounds__(512, 1) void mbpert_kernel(
    const float* __restrict__ x, const float* __restrict__ p,
    const float* __restrict__ r, const float* __restrict__ eps,
    const short* __restrict__ Aw, unsigned* __restrict__ ctr,
    unsigned long long* __restrict__ Ybuf, float* __restrict__ out)
{
    __shared__ __align__(16) char Alds[128 * 1024]; // this WG's 128 A rows, frag order
    __shared__ __align__(16) char Ylds[16 * 1024];  // full 512-row x 16-col Y, bf16, swizzled

    const int bid  = blockIdx.x;
    const int g    = bid >> 2;        // column group: cols [g*16, g*16+16)
    const int q    = bid & 3;         // row quarter: rows [q*128, q*128+128)
    const int tid  = threadIdx.x;
    const int wave = tid >> 6;        // 0..7
    const int lane = tid & 63;
    const int cl   = lane & 15;       // MFMA col
    const int gq   = lane >> 4;
    const int col  = g * 16 + cl;
    const int swz  = (cl & 7) << 4;   // Ylds XOR swizzle (bits 4-6)
    const int rloc = wave * 16 + gq * 4;   // local row base (0..127), mult of 4
    const int rg   = q * 128 + rloc;       // global row base

    unsigned* cptr = ctr + g * 32;    // group counter, 128B padded

    // ---- one-time: stage this WG's 128x512 A slice (128 KB, frag order) into LDS ----
    {
        const short* Asl = Aw + q * 65536;   // contiguous frag block for rows [q*128, ..)
#pragma unroll
        for (int i = 0; i < 16; ++i) {
            size_t slot = (size_t)i * 512 + tid;        // 16B slots
            *(short8*)(Alds + slot * 16) = *(const short8*)(Asl + slot * 8);
        }
    }

    // ---- per-thread state: 4 rows x 1 col ----
    f32x4 X0, W, K1, K2, K3, K4, K5;
    X0 = *(const f32x4*)(x + col * 512 + rg);           // Fortran x[col*512+row]
#pragma unroll
    for (int j = 0; j < 4; ++j) {
        const int row = rg + j;
        W[j] = r[row] + eps[row] * p[row * 1024 + col]; // stage-invariant r + eps*p
    }
    __syncthreads();   // Alds ready

    int ex = 0;        // exchange index 0..599

    // One RK stage: publish Y -> LLC-mediated 4-WG sync -> full Y in Ylds -> A@Y -> k
    // Slice geometry in ull (8B) units: slot = 4KB = 512 ull; col stride 32 ull.
    auto STAGE = [&](f32x4 Yv) -> f32x4 {
        // pack own 4 values to bf16
        unsigned lo = (unsigned)f2bf(Yv[0]) | ((unsigned)f2bf(Yv[1]) << 16);
        unsigned hi = (unsigned)f2bf(Yv[2]) | ((unsigned)f2bf(Yv[3]) << 16);
        uint2v u; u.x = lo; u.y = hi;
        // own rows -> Ylds (previous stage's trailing barrier makes this safe)
        *(uint2v*)(Ylds + cl * 1024 + ((rg * 2) ^ swz)) = u;
        // own rows -> LLC slot [par][g][q], layout [col][row_local] bf16.
        // Relaxed AGENT-scope atomic store: completes at the LLC coherence point,
        // so no cache-maintenance fence is needed for cross-XCD visibility.
        unsigned long long* slot = Ybuf + ((size_t)((ex & 1) * 64 + g) * 4 + q) * 512;
        unsigned long long val = (unsigned long long)lo | ((unsigned long long)hi << 32);
        __hip_atomic_store(slot + (cl * 32 + (rloc >> 2)), val,
                           __ATOMIC_RELAXED, __HIP_MEMORY_SCOPE_AGENT);

        asm volatile("s_waitcnt vmcnt(0)" ::: "memory");  // own stores at LLC
        __syncthreads();                                  // whole WG published
        if (tid == 0) atomicAdd(cptr, 1u);                // device-scope RMW at LLC
        const unsigned tgt = 4u * (unsigned)(ex + 1);
        if (wave == 0) {                                  // single-wave spin, backoff
            while (__hip_atomic_load(cptr, __ATOMIC_RELAXED, __HIP_MEMORY_SCOPE_AGENT) < tgt)
                __builtin_amdgcn_s_sleep(1);
        }
        __syncthreads();                                  // release other 7 waves
        asm volatile("" ::: "memory");                    // no hoisting of peer loads

        // pull 3 peers' 4KB slices -> Ylds (32 consecutive tids = 256B coalesced run)
        const int pcol = tid >> 5;        // 0..15
        const int prq  = tid & 31;        // row quad 0..31
        const unsigned long long* pb = Ybuf + (size_t)((ex & 1) * 64 + g) * 4 * 512;
#pragma unroll
        for (int j = 1; j <= 3; ++j) {
            const int qq = (q + j) & 3;
            unsigned long long v = __hip_atomic_load(pb + qq * 512 + pcol * 32 + prq,
                                                     __ATOMIC_RELAXED, __HIP_MEMORY_SCOPE_AGENT);
            uint2v w; w.x = (unsigned)v; w.y = (unsigned)(v >> 32);
            const int prg = qq * 128 + prq * 4;
            *(uint2v*)(Ylds + pcol * 1024 + ((prg * 2) ^ ((pcol & 7) << 4))) = w;
        }
        __syncthreads();          // full Y ready

        // Z = A_slice @ Y for this wave's 16x16 tile
        f32x4 acc = (f32x4){0.f, 0.f, 0.f, 0.f};
#pragma unroll
        for (int kk = 0; kk < 16; ++kk) {
            short8 a = *(const short8*)(Alds + (wave * 16 + kk) * 1024 + lane * 16);
            short8 b = *(const short8*)(Ylds + cl * 1024 + ((kk * 64 + gq * 16) ^ swz));
            acc = __builtin_amdgcn_mfma_f32_16x16x32_bf16(a, b, acc, 0, 0, 0);
        }
        __syncthreads();          // Ylds consumption done (next stage overwrites)
        ++ex;
        return Yv * (W + acc);
    };

#pragma unroll 1
    for (int s = 0; s < NSTEPS; ++s) {
        K1 = STAGE(X0);
        K2 = STAGE(X0 + HSTEP * (A21 * K1));
        K3 = STAGE(X0 + HSTEP * (A31 * K1 + A32 * K2));
        K4 = STAGE(X0 + HSTEP * (A41 * K1 + A42 * K2 + A43 * K3));
        K5 = STAGE(X0 + HSTEP * (A51 * K1 + A52 * K2 + A53 * K3 + A54 * K4));
        f32x4 K6 = STAGE(X0 + HSTEP * (A61 * K1 + A62 * K2 + A63 * K3 + A64 * K4 + A65 * K5));
        X0 = X0 + HSTEP * (B1 * K1 + B3 * K3 + B4 * K4 + B5 * K5 + B6 * K6);
    }

    // Fortran flatten: out[col*512 + row]
    *(f32x4*)(out + col * 512 + rg) = X0;
}

extern "C" void kernel_launch(void* const* d_in, const int* in_sizes, int n_in,
                              void* d_out, int out_size, void* d_ws, size_t ws_size,
                              hipStream_t stream)
{
    const float* x   = (const float*)d_in[0];
    const float* p   = (const float*)d_in[1];
    const float* r   = (const float*)d_in[2];
    const float* A   = (const float*)d_in[3];
    const float* eps = (const float*)d_in[4];
    float* out = (float*)d_out;

    short*              Aw   = (short*)d_ws;
    unsigned*           ctr  = (unsigned*)((char*)d_ws + WS_CTR);
    unsigned long long* Ybuf = (unsigned long long*)((char*)d_ws + WS_YB);

    hipMemsetAsync(ctr, 0, 64 * 128, stream);               // zero group counters
    hipLaunchKernelGGL(pack_A_kernel, dim3(128), dim3(256), 0, stream, A, Aw);
    hipLaunchKernelGGL(mbpert_kernel, dim3(256), dim3(512), 0, stream,
                       x, p, r, eps, Aw, ctr, Ybuf, out);
}